// Round 3
// baseline (211.963 us; speedup 1.0000x reference)
//
#include <hip/hip_runtime.h>
#include <hip/hip_bf16.h>

// Problem constants (reference: B=2, N=20000, K=16, DIM=256)
// Established facts (R1-R13):
//   - float tensors fp32; idx int32/int64 runtime-detected; d_out fp32
//   - MFMA 16x16x32_bf16 gemm-BT fragments + C/D map verified
//   - R5-R8: global->VGPR weight loads serialize; use LDS (DMA) for weights.
//   - R11: final weight-stationary (640->32 MB weight traffic): total -18.6.
//   - R12: geom MFMA rewrite: kernel work down ~10x but total only -1.7 ->
//     geom is LATENCY/round-bound (1 pair/wave, serial chain, low occupancy),
//     not throughput-bound.
//   - R13 (this round): geom -> persistent waves (8 pairs/wave loop, weights
//     hoisted once/wave, prefetch); final -> single-A-pass: 128 rows/block,
//     A-frags in regs ONCE, two col-half phases vs 128 KB LDS weights
//     (A-traffic 163->102 MB, B-LDS reads halved per output).
//   - LDS quarter-wave phasing: ds_read_b128 with addr = f(r)*16 + q*const
//     (const = multiple of 1 KB) is conflict-free (R9/R11 measured 0).
#define BN   40000
#define NPTS 20000
#define KNN  16
#define DIM  256

typedef __attribute__((ext_vector_type(8))) short bf16x8;   // 8 bf16 = 4 VGPRs
typedef __attribute__((ext_vector_type(4))) float f32x4;
typedef __attribute__((ext_vector_type(16))) float f32x16;

__device__ __forceinline__ float lrelu(float v) { return fmaxf(v, 0.1f * v); }
__device__ __forceinline__ float bs2f(short s) {
    union { unsigned u; float f; } c; c.u = ((unsigned)(unsigned short)s) << 16;
    return c.f;
}
__device__ __forceinline__ short f2bs(float f) {
    __hip_bfloat16 h = __float2bfloat16(f);           // RNE
    return *reinterpret_cast<short*>(&h);
}
__device__ __forceinline__ bf16x8 ldf32_bf16x8(const float* p) {
    const float4 a = ((const float4*)p)[0];
    const float4 b = ((const float4*)p)[1];
    bf16x8 r;
    r[0]=f2bs(a.x); r[1]=f2bs(a.y); r[2]=f2bs(a.z); r[3]=f2bs(a.w);
    r[4]=f2bs(b.x); r[5]=f2bs(b.y); r[6]=f2bs(b.z); r[7]=f2bs(b.w);
    return r;
}

// async global->LDS, 16 B per lane; lds dst = wave-uniform base + lane*16.
__device__ __forceinline__ void dma16(const void* g, void* l) {
    __builtin_amdgcn_global_load_lds(
        (const __attribute__((address_space(1))) unsigned int*)g,
        (__attribute__((address_space(3))) unsigned int*)l, 16, 0, 0);
}

// ---------------------------------------------------------------------------
// geom MLPs via MFMA (blocks 0..624, persistent waves: 8 point-pairs each) +
// idx-dtype detect (block 625) + weight conversion (blocks 626..769).
// geom: wave = blockIdx*4+wv handles pairs [w*8, w*8+8). Weights/biases
//   hoisted ONCE per wave; geom float4 of pair i+1 prefetched during pair i.
//   A = [32 x K16] (rows = 2x16 neighbors, cols 0..3 real), 6 B-tiles cover
//   192 channels. C: col=lane&31, row=(reg&3)+8*(reg>>2)+4*(lane>>5);
//   per-point mean = 8-reg in-lane lrelu-sum + shfl_xor(32).
// conv: Wf,Wi -> kk-tiled bf16 Wt[kk][mat][q][n][8] (32 KB per kk slice);
//       W_init -> kk-tiled Wnt[kk][q][n<64][8] (32 KB total).
// ---------------------------------------------------------------------------
__global__ void __launch_bounds__(256) geom_kernel(
    const float* __restrict__ geom,      // [BN,16,4]
    const float* __restrict__ W1, const float* __restrict__ B1,   // [64,4],[64]
    const float* __restrict__ W2, const float* __restrict__ B2,   // [128,4],[128]
    const int* __restrict__ idxw, int* __restrict__ flag,
    const float* __restrict__ Wf, const float* __restrict__ Wi,   // [256,256]
    const float* __restrict__ Wn,                                  // [64,256]
    short* __restrict__ Wt, short* __restrict__ Wnt,
    __hip_bfloat16* __restrict__ x2,     // [BN,128]
    __hip_bfloat16* __restrict__ x3)     // [BN,256]
{
    if (blockIdx.x >= 626) {             // ---- weight-convert blocks ----
        int t = (blockIdx.x - 626) * 256 + threadIdx.x;   // < 36864 exactly
        if (t < 32768) {                 // Wf (t<16384) / Wi -> tiled Wt
            int mat = (t >> 14) & 1;
            int tt  = t & 16383;
            float4 v = mat ? ((const float4*)Wi)[tt] : ((const float4*)Wf)[tt];
            int n  = tt >> 6;
            int k  = (tt & 63) * 4;
            int kk = k >> 5, q = (k >> 3) & 3, j = k & 7;
            short4 o; o.x=f2bs(v.x); o.y=f2bs(v.y); o.z=f2bs(v.z); o.w=f2bs(v.w);
            *(short4*)(Wt + ((size_t)((kk*2 + mat)*4 + q))*2048 + n*8 + j) = o;
        } else {                          // W_init -> tiled Wnt (n<64)
            int tt = t - 32768;           // < 4096
            float4 v = ((const float4*)Wn)[tt];
            int n  = tt >> 6;
            int k  = (tt & 63) * 4;
            int kk = k >> 5, q = (k >> 3) & 3, j = k & 7;
            short4 o; o.x=f2bs(v.x); o.y=f2bs(v.y); o.z=f2bs(v.z); o.w=f2bs(v.w);
            *(short4*)(Wnt + ((size_t)((kk*4 + q)*64 + n))*8 + j) = o;
        }
        return;
    }
    if (blockIdx.x == 625) {             // ---- detect block (no atomics) ----
        __shared__ int red[256];
        int t = threadIdx.x;
        int v = 0;
#pragma unroll
        for (int it = 0; it < 64; ++it)
            v |= idxw[2 * (t + it * 256) + 1];       // odd words, first 128 KB
        red[t] = v;
        __syncthreads();
        for (int s = 128; s > 0; s >>= 1) {
            if (t < s) red[t] |= red[t + s];
            __syncthreads();
        }
        if (t == 0) *flag = (red[0] != 0) ? 1 : 0;
        return;
    }
    // ---- geom blocks: 625 x 4 waves x 8 pairs = 20000 pairs = 40000 pts ----
    const int lane = threadIdx.x & 63;
    const int wv   = threadIdx.x >> 6;
    const int c31  = lane & 31;
    const int hi   = lane >> 5;
    const int wglob = blockIdx.x * 4 + wv;            // 0..2499

    // B-frags + biases: hoisted ONCE per wave.
    // tiles 0-1 = W1 (64 ch -> x2), 2-5 = W2 (128 ch -> x3)
    bf16x8 bfr[6]; float bv[6];
#pragma unroll
    for (int tt = 0; tt < 6; ++tt) {
        bfr[tt] = (bf16x8){0,0,0,0,0,0,0,0};
        const float* Wrow;
        if (tt < 2) { Wrow = W1 + (size_t)(tt*32 + c31) * 4;     bv[tt] = B1[tt*32 + c31]; }
        else        { Wrow = W2 + (size_t)((tt-2)*32 + c31) * 4; bv[tt] = B2[(tt-2)*32 + c31]; }
        if (hi == 0) {
            const float4 w4 = *(const float4*)Wrow;
            bfr[tt][0]=f2bs(w4.x); bfr[tt][1]=f2bs(w4.y);
            bfr[tt][2]=f2bs(w4.z); bfr[tt][3]=f2bs(w4.w);
        }
    }
    f32x16 ZR;
#pragma unroll
    for (int i = 0; i < 16; ++i) ZR[i] = 0.f;

    // prefetch pair 0's geom data
    float4 g = (float4){0.f,0.f,0.f,0.f};
    if (hi == 0)
        g = *(const float4*)(geom +
            ((size_t)((wglob * 8) * 2 + (c31 >> 4)) * KNN + (c31 & 15)) * 4);

#pragma unroll
    for (int it = 0; it < 8; ++it) {
        const int p0 = (wglob * 8 + it) * 2;
        const float4 gc = g;
        if (it < 7 && hi == 0)                        // prefetch next pair
            g = *(const float4*)(geom +
                ((size_t)(p0 + 2 + (c31 >> 4)) * KNN + (c31 & 15)) * 4);

        // A-frag: row = lane&31 -> (pt = row>>4, k = row&15); cols 0..3 real.
        bf16x8 a = (bf16x8){0,0,0,0,0,0,0,0};
        if (hi == 0) { a[0]=f2bs(gc.x); a[1]=f2bs(gc.y); a[2]=f2bs(gc.z); a[3]=f2bs(gc.w); }

        f32x16 acc[6];
#pragma unroll
        for (int tt = 0; tt < 6; ++tt)
            acc[tt] = __builtin_amdgcn_mfma_f32_32x32x16_bf16(a, bfr[tt], ZR, 0, 0, 0);

        // Epilogue: regs 0-7 -> pt A rows, 8-15 -> pt B rows; each lane covers
        // 8 of 16 rows of each point; shfl_xor(32) completes the mean.
#pragma unroll
        for (int tt = 0; tt < 6; ++tt) {
            float sA = 0.f, sB = 0.f;
#pragma unroll
            for (int i = 0; i < 8; ++i)  sA += lrelu(acc[tt][i]     + bv[tt]);
#pragma unroll
            for (int i = 0; i < 8; ++i)  sB += lrelu(acc[tt][i + 8] + bv[tt]);
            sA += __shfl_xor(sA, 32, 64);
            sB += __shfl_xor(sB, 32, 64);
            const float s = (hi ? sB : sA) * (1.f / 16.f);
            const short v = f2bs(s);
            if (tt < 2) ((short*)x2)[(size_t)(p0 + hi) * 128 + tt*32 + c31] = v;
            else        ((short*)x3)[(size_t)(p0 + hi) * 256 + (tt-2)*32 + c31] = v;
        }
    }
}

// ---------------------------------------------------------------------------
// x1 = LR(input @ W_init^T + b_init), MFMA. Weights (32 KB tiled) DMA'd to
// LDS once, ONE barrier; A-frags hoisted as a 16-load burst before barrier;
// inner loop = pure ds_read + MFMA. Block = 64 rows (4 waves x 16). Grid 625.
// x1 lives in d_out scratch (consumed by gather1 before final overwrites).
// ---------------------------------------------------------------------------
__global__ void __launch_bounds__(256) mlp_init_mfma(
    const float* __restrict__ X,     // [BN,256]
    const short* __restrict__ Wnt,   // [kk][q][64][8] bf16, 32 KB
    const float* __restrict__ bias,  // [64]
    __hip_bfloat16* __restrict__ Y)  // [BN,64] bf16 (d_out scratch)
{
    __shared__ short wbuf[16384];    // 32 KB
    int t = threadIdx.x;
    int wave = t >> 6, lane = t & 63;
    int r = lane & 15, q = lane >> 4;
    // DMA the full 32 KB (4 waves x 8 x 1 KB, linear copy)
    {
        const char* W8 = (const char*)Wnt;
        char* L8 = (char*)wbuf;
#pragma unroll
        for (int rd = 0; rd < 8; ++rd) {
            int off = (wave * 8 + rd) * 1024 + lane * 16;
            dma16(W8 + off, L8 + off);
        }
    }
    int m0 = blockIdx.x * 64 + wave * 16;
    const float* Xs = X + (size_t)(m0 + r) * DIM + q * 8;
    bf16x8 a[8];
#pragma unroll
    for (int kk = 0; kk < 8; ++kk) a[kk] = ldf32_bf16x8(Xs + kk * 32);
    __syncthreads();

    f32x4 acc[4];
#pragma unroll
    for (int nt = 0; nt < 4; ++nt) acc[nt] = (f32x4){0.f,0.f,0.f,0.f};
#pragma unroll
    for (int kk = 0; kk < 8; ++kk) {
#pragma unroll
        for (int nt = 0; nt < 4; ++nt) {
            bf16x8 b = *(const bf16x8*)&wbuf[((kk*4 + q)*64 + nt*16 + r) * 8];
            acc[nt] = __builtin_amdgcn_mfma_f32_16x16x32_bf16(a[kk], b, acc[nt], 0, 0, 0);
        }
    }
#pragma unroll
    for (int nt = 0; nt < 4; ++nt) {
        int col = nt * 16 + r;
        float bvx = bias[col];
#pragma unroll
        for (int i = 0; i < 4; ++i) {
            float v = lrelu(acc[nt][i] + bvx);
            Y[(size_t)(m0 + q*4 + i) * 64 + col] = __float2bfloat16(v);
        }
    }
}

// ---------------------------------------------------------------------------
// gather-mean of x1 rows -> x2[:,64:128]. 8 lanes/point; each lane loads 2
// indices, neighbors broadcast via __shfl (no redundant idx loads).
// ---------------------------------------------------------------------------
__global__ void __launch_bounds__(256) gather1_kernel(
    const int* __restrict__ idxw, const int* __restrict__ flag,
    const __hip_bfloat16* __restrict__ x1,    // [BN,64]
    __hip_bfloat16* __restrict__ x2)          // [BN,128]
{
    int t = blockIdx.x * 256 + threadIdx.x;   // 320000 exactly = BN*8
    int p = t >> 3, j = t & 7;
    int lane = threadIdx.x & 63;
    int dual = (*flag == 0) ? 2 : 1;
    int base = (p >= NPTS) ? NPTS : 0;
    int i0 = idxw[((size_t)p * 16 + 2*j)     * dual];   // neighbor 2j
    int i1 = idxw[((size_t)p * 16 + 2*j + 1) * dual];   // neighbor 2j+1
    int g8 = lane & 56;
    float acc[8];
#pragma unroll
    for (int i = 0; i < 8; ++i) acc[i] = 0.f;
#pragma unroll
    for (int k = 0; k < 8; ++k) {
        int rA = base + __shfl(i0, g8 + k, 64);         // neighbor 2k
        int rB = base + __shfl(i1, g8 + k, 64);         // neighbor 2k+1
        bf16x8 vA = *(const bf16x8*)((const short*)x1 + (size_t)rA * 64 + j * 8);
        bf16x8 vB = *(const bf16x8*)((const short*)x1 + (size_t)rB * 64 + j * 8);
#pragma unroll
        for (int i = 0; i < 8; ++i) acc[i] += bs2f(vA[i]) + bs2f(vB[i]);
    }
    bf16x8 o;
#pragma unroll
    for (int i = 0; i < 8; ++i) o[i] = f2bs(acc[i] * (1.f/16.f));
    *(bf16x8*)((short*)x2 + (size_t)p * 128 + 64 + j * 8) = o;
}

// ---------------------------------------------------------------------------
// gather-mean of x2 rows -> x3[:,128:256]. 16 lanes/point; each lane loads 1
// index, neighbors broadcast via __shfl.
// ---------------------------------------------------------------------------
__global__ void __launch_bounds__(256) gather2_kernel(
    const int* __restrict__ idxw, const int* __restrict__ flag,
    const __hip_bfloat16* __restrict__ x2,    // [BN,128]
    __hip_bfloat16* __restrict__ x3)          // [BN,256]
{
    int t = blockIdx.x * 256 + threadIdx.x;   // 640000 exactly = BN*16
    int p = t >> 4, j = t & 15;
    int lane = threadIdx.x & 63;
    int dual = (*flag == 0) ? 2 : 1;
    int base = (p >= NPTS) ? NPTS : 0;
    int myi = idxw[((size_t)p * 16 + j) * dual];
    int g16 = lane & 48;
    float acc[8];
#pragma unroll
    for (int i = 0; i < 8; ++i) acc[i] = 0.f;
#pragma unroll
    for (int k = 0; k < KNN; ++k) {
        int row = base + __shfl(myi, g16 + k, 64);
        bf16x8 v = *(const bf16x8*)((const short*)x2 + (size_t)row * 128 + j * 8);
#pragma unroll
        for (int i = 0; i < 8; ++i) acc[i] += bs2f(v[i]);
    }
    bf16x8 o;
#pragma unroll
    for (int i = 0; i < 8; ++i) o[i] = f2bs(acc[i] * (1.f/16.f));
    *(bf16x8*)((short*)x3 + (size_t)p * 256 + 128 + j * 8) = o;
}

// ---------------------------------------------------------------------------
// out = LR(x3 @ Wf^T + bf) + LR(input @ Wi^T + bi), fp32 out. MFMA.
// R13 single-A-pass: grid 313 x 128 rows. 8 waves = 4 rg x 2 cg; each wave
// owns 2 row-tiles (rt) x 64 cols. A-frags (X3 bf16 + RES fp32->bf16) loaded
// ONCE into regs. Two phases h=0,1 over col-halves: 128 KB LDS = col-half of
// BOTH mats; phase-1 DMA issued after phase-0 MFMAs, overlapped with phase-0
// epilogue stores. 3 barriers total, inner loop pure ds_read+MFMA.
// B-read byte addr = const + q*2048 + r*16 -> quarter-wave conflict-free.
// ---------------------------------------------------------------------------
__global__ void __launch_bounds__(512, 2) final_mfma(
    const __hip_bfloat16* __restrict__ X3,    // [BN,256] bf16 ws
    const float* __restrict__ RES,            // [BN,256] fp32
    const short* __restrict__ Wt,             // tiled bf16 [kk][mat][q][n][8]
    const float* __restrict__ Bf,             // [256]
    const float* __restrict__ Bi,             // [256]
    float* __restrict__ OUT)                  // [BN,256] fp32
{
    __shared__ short lw[65536];               // 128 KB: col-half, both mats
    const int t    = threadIdx.x;
    const int wave = t >> 6, lane = t & 63;
    const int r = lane & 15, q = lane >> 4;
    const int rg = wave >> 1, cg = wave & 1;  // 4 row-groups x 2 col-groups
    const int p0 = blockIdx.x * 128;          // 313 blocks: 312 full + tail
    const bool live1 = (p0 + 128) <= BN;      // rt=1 tile valid?

    const char* WtB = (const char*)Wt;
    char* L = (char*)lw;
    // ---- DMA phase-0 weights (cols 0..127 of both mats), 64 chunks x 2 KB
#pragma unroll
    for (int i = 0; i < 16; ++i) {
        int c = wave * 8 + (i >> 1);           // 0..63: (mat*8+kk)*4+qq
        int d = i & 1;                          // half-chunk (1 KB)
        int mat = c >> 5, kk = (c >> 2) & 7, qq = c & 3;
        int src_sh = ((kk * 2 + mat) * 4 + qq) * 2048;          // h=0
        dma16(WtB + (size_t)src_sh * 2 + d * 1024 + lane * 16,
              L + (c * 2 + d) * 1024 + lane * 16);
    }

    // ---- A-frags for both row-tiles, loaded ONCE (overlaps DMA) ----
    bf16x8 a1[2][8], a2[2][8];
#pragma unroll
    for (int rt = 0; rt < 2; ++rt) {
        if (rt == 1 && !live1) {
#pragma unroll
            for (int kk = 0; kk < 8; ++kk) {
                a1[1][kk] = (bf16x8){0,0,0,0,0,0,0,0};
                a2[1][kk] = (bf16x8){0,0,0,0,0,0,0,0};
            }
        } else {
            const int row = p0 + rt * 64 + rg * 16 + r;
            const short* x3r = (const short*)X3 + (size_t)row * DIM + q * 8;
            const float* rsr = RES + (size_t)row * DIM + q * 8;
#pragma unroll
            for (int kk = 0; kk < 8; ++kk) {
                a1[rt][kk] = *(const bf16x8*)(x3r + kk * 32);
                a2[rt][kk] = ldf32_bf16x8(rsr + kk * 32);
            }
        }
    }

    const short* bp = lw + q * 1024 + (cg * 64 + r) * 8;  // +(mat*8+kk)*4096+nt*128

#pragma unroll
    for (int h = 0; h < 2; ++h) {
        const int cb = h * 128 + cg * 64;
        float bfv[4], biv[4];
#pragma unroll
        for (int nt = 0; nt < 4; ++nt) {
            bfv[nt] = Bf[cb + nt * 16 + r];
            biv[nt] = Bi[cb + nt * 16 + r];
        }
        __syncthreads();                      // DMA(h) drained, weights ready

        f32x4 acc1[2][4], acc2[2][4];
#pragma unroll
        for (int rt = 0; rt < 2; ++rt)
#pragma unroll
            for (int nt = 0; nt < 4; ++nt) {
                acc1[rt][nt] = (f32x4){0.f,0.f,0.f,0.f};
                acc2[rt][nt] = (f32x4){0.f,0.f,0.f,0.f};
            }
#pragma unroll
        for (int kk = 0; kk < 8; ++kk) {
#pragma unroll
            for (int nt = 0; nt < 4; ++nt) {
                bf16x8 b1 = *(const bf16x8*)(bp + kk * 4096 + nt * 128);
                bf16x8 b2 = *(const bf16x8*)(bp + 32768 + kk * 4096 + nt * 128);
                acc1[0][nt] = __builtin_amdgcn_mfma_f32_16x16x32_bf16(a1[0][kk], b1, acc1[0][nt], 0, 0, 0);
                acc2[0][nt] = __builtin_amdgcn_mfma_f32_16x16x32_bf16(a2[0][kk], b2, acc2[0][nt], 0, 0, 0);
                acc1[1][nt] = __builtin_amdgcn_mfma_f32_16x16x32_bf16(a1[1][kk], b1, acc1[1][nt], 0, 0, 0);
                acc2[1][nt] = __builtin_amdgcn_mfma_f32_16x16x32_bf16(a2[1][kk], b2, acc2[1][nt], 0, 0, 0);
            }
        }
        if (h == 0) {
            __syncthreads();                  // all waves done reading LDS h=0
            // ---- DMA phase-1 weights (cols 128..255), overlapped w/ epilogue
#pragma unroll
            for (int i = 0; i < 16; ++i) {
                int c = wave * 8 + (i >> 1);
                int d = i & 1;
                int mat = c >> 5, kk2 = (c >> 2) & 7, qq = c & 3;
                int src_sh = ((kk2 * 2 + mat) * 4 + qq) * 2048 + 1024;  // h=1
                dma16(WtB + (size_t)src_sh * 2 + d * 1024 + lane * 16,
                      L + (c * 2 + d) * 1024 + lane * 16);
            }
        }
        // ---- epilogue: 2 rt x 4 nt x 4 rows, 64 cols per wave ----
#pragma unroll
        for (int rt = 0; rt < 2; ++rt) {
            if (rt == 0 || live1) {
#pragma unroll
                for (int nt = 0; nt < 4; ++nt) {
                    const int col = cb + nt * 16 + r;
#pragma unroll
                    for (int i = 0; i < 4; ++i) {
                        float v = lrelu(acc1[rt][nt][i] + bfv[nt])
                                + lrelu(acc2[rt][nt][i] + biv[nt]);
                        OUT[(size_t)(p0 + rt*64 + rg*16 + q*4 + i) * DIM + col] = v;
                    }
                }
            }
        }
    }
}

// ---------------------------------------------------------------------------
extern "C" void kernel_launch(void* const* d_in, const int* in_sizes, int n_in,
                              void* d_out, int out_size, void* d_ws, size_t ws_size,
                              hipStream_t stream)
{
    const float* input  = (const float*)d_in[0];   // [2,20000,256]
    const float* geom   = (const float*)d_in[1];   // [2,20000,16,4]
    const int*   idxw   = (const int*)d_in[2];     // int32/int64 (detected)
    const float* W_init = (const float*)d_in[3];   // [64,256]
    const float* b_init = (const float*)d_in[4];
    const float* W_l1   = (const float*)d_in[5];   // [64,4]
    const float* b_l1   = (const float*)d_in[6];
    const float* W_l2   = (const float*)d_in[7];   // [128,4]
    const float* b_l2   = (const float*)d_in[8];
    const float* W_fin  = (const float*)d_in[9];   // [256,256]
    const float* b_fin  = (const float*)d_in[10];
    const float* W_id   = (const float*)d_in[11];  // [256,256]
    const float* b_id   = (const float*)d_in[12];
    float* out = (float*)d_out;                    // [2,20000,256] fp32

    // ws layout (<= 35.84 MB, proven safe R4-R10):
    //   flag @0 (16B)
    //   Wt  tiled bf16 256KB @16 ; Wnt tiled bf16 32KB @16+262144
    //   x2  [BN,128] bf16 @16+5.12e6
    //   x3  [BN,256] bf16 @16+15.36e6
    // x1 [BN,64] bf16 lives in d_out scratch; consumed by gather1, then
    // final_mfma overwrites all of d_out.
    char* ws = (char*)d_ws;
    int* flag = (int*)ws;
    short* Wt  = (short*)(ws + 16);
    short* Wnt = (short*)(ws + 16 + 262144);
    __hip_bfloat16* x2 = (__hip_bfloat16*)(ws + 16 + 5120000);
    __hip_bfloat16* x3 = (__hip_bfloat16*)(ws + 16 + 15360000);
    __hip_bfloat16* x1 = (__hip_bfloat16*)d_out;   // scratch, dead after gather1

    geom_kernel<<<770, 256, 0, stream>>>(geom, W_l1, b_l1, W_l2, b_l2,
                                         idxw, flag, W_fin, W_id, W_init,
                                         Wt, Wnt, x2, x3);
    mlp_init_mfma<<<625, 256, 0, stream>>>(input, Wnt, b_init, x1);
    gather1_kernel<<<1250, 256, 0, stream>>>(idxw, flag, x1, x2);
    gather2_kernel<<<2500, 256, 0, stream>>>(idxw, flag, x2, x3);
    final_mfma<<<313, 512, 0, stream>>>(x3, input, Wt, b_fin, b_id, out);
}

// Round 4
// 195.798 us; speedup vs baseline: 1.0826x; 1.0826x over previous
//
#include <hip/hip_runtime.h>
#include <hip/hip_bf16.h>

// Problem constants (reference: B=2, N=20000, K=16, DIM=256)
// Established facts (R1-R14):
//   - float tensors fp32; idx int32/int64 runtime-detected; d_out fp32
//   - MFMA 16x16x32_bf16 gemm-BT fragments + C/D map verified
//   - R5-R8: global->VGPR weight loads serialize; use LDS (DMA) for weights.
//   - R11: final weight-stationary (250 blks x 512 thr, 128 KB LDS, ONE
//     barrier, 5x64-row tiles) = 39.4 us. KNOWN GOOD.
//   - R13: single-A-pass final (313 blks, 2 phases) = 47 us REGRESSION:
//     1.22 blocks/CU imbalance + 2x weight DMA + mid-kernel barrier stall.
//     Reverted here.
//   - Timeline algebra R0-R3: geom pinned ~40 us across 3 structurally
//     different versions (10x work delta) -> per-dispatch floor, not compute.
//     mlp_init/gather1/gather2+gaps = ~125 us, each < 42 (never in top-5).
//   - R14 (this round): prep split out (convert+detect, ~5 us); geom-MLP and
//     mlp_init CO-DISPATCHED as block-ranges of one kernel (no cross-dep:
//     mlp needs only Wnt from prep). Chain: prep -> [geom||mlp] -> g1 -> g2
//     -> final. Saves one ~15-40 us serialization point.
//   - LDS quarter-wave phasing: ds_read_b128 with addr = f(r)*16 + q*const
//     (const = multiple of 1 KB) is conflict-free (R9/R11 measured 0).
#define BN   40000
#define NPTS 20000
#define KNN  16
#define DIM  256

typedef __attribute__((ext_vector_type(8))) short bf16x8;   // 8 bf16 = 4 VGPRs
typedef __attribute__((ext_vector_type(4))) float f32x4;
typedef __attribute__((ext_vector_type(16))) float f32x16;

__device__ __forceinline__ float lrelu(float v) { return fmaxf(v, 0.1f * v); }
__device__ __forceinline__ float bs2f(short s) {
    union { unsigned u; float f; } c; c.u = ((unsigned)(unsigned short)s) << 16;
    return c.f;
}
__device__ __forceinline__ short f2bs(float f) {
    __hip_bfloat16 h = __float2bfloat16(f);           // RNE
    return *reinterpret_cast<short*>(&h);
}
__device__ __forceinline__ bf16x8 ldf32_bf16x8(const float* p) {
    const float4 a = ((const float4*)p)[0];
    const float4 b = ((const float4*)p)[1];
    bf16x8 r;
    r[0]=f2bs(a.x); r[1]=f2bs(a.y); r[2]=f2bs(a.z); r[3]=f2bs(a.w);
    r[4]=f2bs(b.x); r[5]=f2bs(b.y); r[6]=f2bs(b.z); r[7]=f2bs(b.w);
    return r;
}

// async global->LDS, 16 B per lane; lds dst = wave-uniform base + lane*16.
__device__ __forceinline__ void dma16(const void* g, void* l) {
    __builtin_amdgcn_global_load_lds(
        (const __attribute__((address_space(1))) unsigned int*)g,
        (__attribute__((address_space(3))) unsigned int*)l, 16, 0, 0);
}

// ---------------------------------------------------------------------------
// prep: idx-dtype detect (block 0) + weight conversion (blocks 1..144).
// conv: Wf,Wi -> kk-tiled bf16 Wt[kk][mat][q][n][8] (32 KB per kk slice);
//       W_init -> kk-tiled Wnt[kk][q][n<64][8] (32 KB total).
// Tiny dispatch (~5 us) so the two big stage-2 kernels can co-dispatch.
// ---------------------------------------------------------------------------
__global__ void __launch_bounds__(256) prep_kernel(
    const int* __restrict__ idxw, int* __restrict__ flag,
    const float* __restrict__ Wf, const float* __restrict__ Wi,   // [256,256]
    const float* __restrict__ Wn,                                  // [64,256]
    short* __restrict__ Wt, short* __restrict__ Wnt)
{
    if (blockIdx.x == 0) {               // ---- detect block (no atomics) ----
        __shared__ int red[256];
        int t = threadIdx.x;
        int v = 0;
#pragma unroll
        for (int it = 0; it < 64; ++it)
            v |= idxw[2 * (t + it * 256) + 1];       // odd words, first 128 KB
        red[t] = v;
        __syncthreads();
        for (int s = 128; s > 0; s >>= 1) {
            if (t < s) red[t] |= red[t + s];
            __syncthreads();
        }
        if (t == 0) *flag = (red[0] != 0) ? 1 : 0;
        return;
    }
    int t = (blockIdx.x - 1) * 256 + threadIdx.x;   // < 36864 exactly
    if (t < 32768) {                 // Wf (t<16384) / Wi -> tiled Wt
        int mat = (t >> 14) & 1;
        int tt  = t & 16383;
        float4 v = mat ? ((const float4*)Wi)[tt] : ((const float4*)Wf)[tt];
        int n  = tt >> 6;
        int k  = (tt & 63) * 4;
        int kk = k >> 5, q = (k >> 3) & 3, j = k & 7;
        short4 o; o.x=f2bs(v.x); o.y=f2bs(v.y); o.z=f2bs(v.z); o.w=f2bs(v.w);
        *(short4*)(Wt + ((size_t)((kk*2 + mat)*4 + q))*2048 + n*8 + j) = o;
    } else {                          // W_init -> tiled Wnt (n<64)
        int tt = t - 32768;           // < 4096
        float4 v = ((const float4*)Wn)[tt];
        int n  = tt >> 6;
        int k  = (tt & 63) * 4;
        int kk = k >> 5, q = (k >> 3) & 3, j = k & 7;
        short4 o; o.x=f2bs(v.x); o.y=f2bs(v.y); o.z=f2bs(v.z); o.w=f2bs(v.w);
        *(short4*)(Wnt + ((size_t)((kk*4 + q)*64 + n))*8 + j) = o;
    }
}

// ---------------------------------------------------------------------------
// stage2: geom MLPs (blocks 0..624) CO-DISPATCHED with mlp_init (625..1249).
// No cross-dependence: geom reads geom+W1/W2, writes x2[:,0:64]/x3[:,0:128];
// mlp reads input+Wnt(prep)+b_init, writes x1. Disjoint outputs.
//
// geom (R13 persistent waves): wave = blockIdx*4+wv handles 8 point-pairs.
//   Weights/biases hoisted ONCE per wave; next pair's geom float4 prefetched.
//   A = [32 x K16] (rows = 2x16 neighbors, cols 0..3 real), 6 B-tiles cover
//   192 channels. C: col=lane&31, row=(reg&3)+8*(reg>>2)+4*(lane>>5);
//   per-point mean = 8-reg in-lane lrelu-sum + shfl_xor(32).
//
// mlp_init: x1 = LR(input @ W_init^T + b_init). Weights (32 KB tiled) DMA'd
//   to LDS once, ONE barrier; A-frags hoisted before barrier; inner loop =
//   pure ds_read + MFMA. 64 rows/block (4 waves x 16).
//   x1 lives in d_out scratch (consumed by gather1 before final overwrites).
// ---------------------------------------------------------------------------
__global__ void __launch_bounds__(256) stage2_kernel(
    const float* __restrict__ geom,      // [BN,16,4]
    const float* __restrict__ W1, const float* __restrict__ B1,   // [64,4],[64]
    const float* __restrict__ W2, const float* __restrict__ B2,   // [128,4],[128]
    const float* __restrict__ X,         // [BN,256] input
    const short* __restrict__ Wnt,       // [kk][q][64][8] bf16, 32 KB
    const float* __restrict__ b_init,    // [64]
    __hip_bfloat16* __restrict__ x2,     // [BN,128]
    __hip_bfloat16* __restrict__ x3,     // [BN,256]
    __hip_bfloat16* __restrict__ x1)     // [BN,64] bf16 (d_out scratch)
{
    __shared__ short wbuf[16384];        // 32 KB (used by mlp blocks only)

    if (blockIdx.x >= 625) {             // ---------------- mlp_init ----------
        int bid = blockIdx.x - 625;      // 0..624
        int t = threadIdx.x;
        int wave = t >> 6, lane = t & 63;
        int r = lane & 15, q = lane >> 4;
        // DMA the full 32 KB (4 waves x 8 x 1 KB, linear copy)
        {
            const char* W8 = (const char*)Wnt;
            char* L8 = (char*)wbuf;
#pragma unroll
            for (int rd = 0; rd < 8; ++rd) {
                int off = (wave * 8 + rd) * 1024 + lane * 16;
                dma16(W8 + off, L8 + off);
            }
        }
        int m0 = bid * 64 + wave * 16;
        const float* Xs = X + (size_t)(m0 + r) * DIM + q * 8;
        bf16x8 a[8];
#pragma unroll
        for (int kk = 0; kk < 8; ++kk) a[kk] = ldf32_bf16x8(Xs + kk * 32);
        __syncthreads();

        f32x4 acc[4];
#pragma unroll
        for (int nt = 0; nt < 4; ++nt) acc[nt] = (f32x4){0.f,0.f,0.f,0.f};
#pragma unroll
        for (int kk = 0; kk < 8; ++kk) {
#pragma unroll
            for (int nt = 0; nt < 4; ++nt) {
                bf16x8 b = *(const bf16x8*)&wbuf[((kk*4 + q)*64 + nt*16 + r) * 8];
                acc[nt] = __builtin_amdgcn_mfma_f32_16x16x32_bf16(a[kk], b, acc[nt], 0, 0, 0);
            }
        }
#pragma unroll
        for (int nt = 0; nt < 4; ++nt) {
            int col = nt * 16 + r;
            float bvx = b_init[col];
#pragma unroll
            for (int i = 0; i < 4; ++i) {
                float v = lrelu(acc[nt][i] + bvx);
                x1[(size_t)(m0 + q*4 + i) * 64 + col] = __float2bfloat16(v);
            }
        }
        return;
    }

    // ---------------- geom: 625 blocks x 4 waves x 8 pairs = 40000 pts -----
    const int lane = threadIdx.x & 63;
    const int wv   = threadIdx.x >> 6;
    const int c31  = lane & 31;
    const int hi   = lane >> 5;
    const int wglob = blockIdx.x * 4 + wv;            // 0..2499

    // B-frags + biases: hoisted ONCE per wave.
    // tiles 0-1 = W1 (64 ch -> x2), 2-5 = W2 (128 ch -> x3)
    bf16x8 bfr[6]; float bv[6];
#pragma unroll
    for (int tt = 0; tt < 6; ++tt) {
        bfr[tt] = (bf16x8){0,0,0,0,0,0,0,0};
        const float* Wrow;
        if (tt < 2) { Wrow = W1 + (size_t)(tt*32 + c31) * 4;     bv[tt] = B1[tt*32 + c31]; }
        else        { Wrow = W2 + (size_t)((tt-2)*32 + c31) * 4; bv[tt] = B2[(tt-2)*32 + c31]; }
        if (hi == 0) {
            const float4 w4 = *(const float4*)Wrow;
            bfr[tt][0]=f2bs(w4.x); bfr[tt][1]=f2bs(w4.y);
            bfr[tt][2]=f2bs(w4.z); bfr[tt][3]=f2bs(w4.w);
        }
    }
    f32x16 ZR;
#pragma unroll
    for (int i = 0; i < 16; ++i) ZR[i] = 0.f;

    // prefetch pair 0's geom data
    float4 g = (float4){0.f,0.f,0.f,0.f};
    if (hi == 0)
        g = *(const float4*)(geom +
            ((size_t)((wglob * 8) * 2 + (c31 >> 4)) * KNN + (c31 & 15)) * 4);

#pragma unroll
    for (int it = 0; it < 8; ++it) {
        const int p0 = (wglob * 8 + it) * 2;
        const float4 gc = g;
        if (it < 7 && hi == 0)                        // prefetch next pair
            g = *(const float4*)(geom +
                ((size_t)(p0 + 2 + (c31 >> 4)) * KNN + (c31 & 15)) * 4);

        // A-frag: row = lane&31 -> (pt = row>>4, k = row&15); cols 0..3 real.
        bf16x8 a = (bf16x8){0,0,0,0,0,0,0,0};
        if (hi == 0) { a[0]=f2bs(gc.x); a[1]=f2bs(gc.y); a[2]=f2bs(gc.z); a[3]=f2bs(gc.w); }

        f32x16 acc[6];
#pragma unroll
        for (int tt = 0; tt < 6; ++tt)
            acc[tt] = __builtin_amdgcn_mfma_f32_32x32x16_bf16(a, bfr[tt], ZR, 0, 0, 0);

        // Epilogue: regs 0-7 -> pt A rows, 8-15 -> pt B rows; each lane covers
        // 8 of 16 rows of each point; shfl_xor(32) completes the mean.
#pragma unroll
        for (int tt = 0; tt < 6; ++tt) {
            float sA = 0.f, sB = 0.f;
#pragma unroll
            for (int i = 0; i < 8; ++i)  sA += lrelu(acc[tt][i]     + bv[tt]);
#pragma unroll
            for (int i = 0; i < 8; ++i)  sB += lrelu(acc[tt][i + 8] + bv[tt]);
            sA += __shfl_xor(sA, 32, 64);
            sB += __shfl_xor(sB, 32, 64);
            const float s = (hi ? sB : sA) * (1.f / 16.f);
            const short v = f2bs(s);
            if (tt < 2) ((short*)x2)[(size_t)(p0 + hi) * 128 + tt*32 + c31] = v;
            else        ((short*)x3)[(size_t)(p0 + hi) * 256 + (tt-2)*32 + c31] = v;
        }
    }
}

// ---------------------------------------------------------------------------
// gather-mean of x1 rows -> x2[:,64:128]. 8 lanes/point; each lane loads 2
// indices, neighbors broadcast via __shfl (no redundant idx loads).
// ---------------------------------------------------------------------------
__global__ void __launch_bounds__(256) gather1_kernel(
    const int* __restrict__ idxw, const int* __restrict__ flag,
    const __hip_bfloat16* __restrict__ x1,    // [BN,64]
    __hip_bfloat16* __restrict__ x2)          // [BN,128]
{
    int t = blockIdx.x * 256 + threadIdx.x;   // 320000 exactly = BN*8
    int p = t >> 3, j = t & 7;
    int lane = threadIdx.x & 63;
    int dual = (*flag == 0) ? 2 : 1;
    int base = (p >= NPTS) ? NPTS : 0;
    int i0 = idxw[((size_t)p * 16 + 2*j)     * dual];   // neighbor 2j
    int i1 = idxw[((size_t)p * 16 + 2*j + 1) * dual];   // neighbor 2j+1
    int g8 = lane & 56;
    float acc[8];
#pragma unroll
    for (int i = 0; i < 8; ++i) acc[i] = 0.f;
#pragma unroll
    for (int k = 0; k < 8; ++k) {
        int rA = base + __shfl(i0, g8 + k, 64);         // neighbor 2k
        int rB = base + __shfl(i1, g8 + k, 64);         // neighbor 2k+1
        bf16x8 vA = *(const bf16x8*)((const short*)x1 + (size_t)rA * 64 + j * 8);
        bf16x8 vB = *(const bf16x8*)((const short*)x1 + (size_t)rB * 64 + j * 8);
#pragma unroll
        for (int i = 0; i < 8; ++i) acc[i] += bs2f(vA[i]) + bs2f(vB[i]);
    }
    bf16x8 o;
#pragma unroll
    for (int i = 0; i < 8; ++i) o[i] = f2bs(acc[i] * (1.f/16.f));
    *(bf16x8*)((short*)x2 + (size_t)p * 128 + 64 + j * 8) = o;
}

// ---------------------------------------------------------------------------
// gather-mean of x2 rows -> x3[:,128:256]. 16 lanes/point; each lane loads 1
// index, neighbors broadcast via __shfl.
// ---------------------------------------------------------------------------
__global__ void __launch_bounds__(256) gather2_kernel(
    const int* __restrict__ idxw, const int* __restrict__ flag,
    const __hip_bfloat16* __restrict__ x2,    // [BN,128]
    __hip_bfloat16* __restrict__ x3)          // [BN,256]
{
    int t = blockIdx.x * 256 + threadIdx.x;   // 640000 exactly = BN*16
    int p = t >> 4, j = t & 15;
    int lane = threadIdx.x & 63;
    int dual = (*flag == 0) ? 2 : 1;
    int base = (p >= NPTS) ? NPTS : 0;
    int myi = idxw[((size_t)p * 16 + j) * dual];
    int g16 = lane & 48;
    float acc[8];
#pragma unroll
    for (int i = 0; i < 8; ++i) acc[i] = 0.f;
#pragma unroll
    for (int k = 0; k < KNN; ++k) {
        int row = base + __shfl(myi, g16 + k, 64);
        bf16x8 v = *(const bf16x8*)((const short*)x2 + (size_t)row * 128 + j * 8);
#pragma unroll
        for (int i = 0; i < 8; ++i) acc[i] += bs2f(v[i]);
    }
    bf16x8 o;
#pragma unroll
    for (int i = 0; i < 8; ++i) o[i] = f2bs(acc[i] * (1.f/16.f));
    *(bf16x8*)((short*)x3 + (size_t)p * 256 + 128 + j * 8) = o;
}

// ---------------------------------------------------------------------------
// out = LR(x3 @ Wf^T + bf) + LR(input @ Wi^T + bi), fp32 out. MFMA.
// R11 weight-stationary (KNOWN GOOD, 39.4 us):
//   grid = 250 = 2 col-halves x 125 row-chunks (320 rows each).
//   block = 512 thr (8 waves = 4 row-groups x 2 col-groups of 64 cols).
//   LDS 128 KB = col-half of BOTH mats, remapped from Wt as 64 x 2 KB chunks
//   [(mat*8+kk)*4+q][n_local<128][8], DMA'd ONCE (16 dma16/wave), ONE barrier.
//   Main loop: 5 tiles x 64 rows; A-frags (X3 bf16 direct, RES raw float4 +
//   lazy per-kk cvt) in regs; pure ds_read+MFMA; NO barriers, no W re-fetch.
//   B-read byte addr = const + q*2048 + r*16 -> quarter-wave conflict-free.
// ---------------------------------------------------------------------------
__global__ void __launch_bounds__(512, 2) final_mfma(
    const __hip_bfloat16* __restrict__ X3,    // [BN,256] bf16 ws
    const float* __restrict__ RES,            // [BN,256] fp32
    const short* __restrict__ Wt,             // tiled bf16 [kk][mat][q][n][8]
    const float* __restrict__ Bf,             // [256]
    const float* __restrict__ Bi,             // [256]
    float* __restrict__ OUT)                  // [BN,256] fp32
{
    __shared__ short lw[65536];               // 128 KB: col-half, both mats
    const int t    = threadIdx.x;
    const int wave = t >> 6, lane = t & 63;
    const int r = lane & 15, q = lane >> 4;
    const int rg = wave >> 1, cg = wave & 1;  // 4 row-groups x 2 col-groups
    const int ch = blockIdx.x & 1;            // col-half
    const int p0 = (blockIdx.x >> 1) * 320;   // 125 chunks x 320 rows = 40000

    // ---- prologue: DMA W col-half into LDS, once. 64 chunks x 2 KB.
    // chunk c = (mat*8+kk)*4+qq ; src = Wt[(kk*2+mat)*4+qq] + ch*128 cols.
    {
        const char* WtB = (const char*)Wt;
        char* L = (char*)lw;
#pragma unroll
        for (int i = 0; i < 16; ++i) {
            int c = wave * 8 + (i >> 1);           // 0..63
            int d = i & 1;                          // half-chunk (1 KB)
            int mat = c >> 5, kk = (c >> 2) & 7, qq = c & 3;
            int src_sh = ((kk * 2 + mat) * 4 + qq) * 2048 + ch * 1024;
            dma16(WtB + (size_t)src_sh * 2 + d * 1024 + lane * 16,
                  L + (c * 2 + d) * 1024 + lane * 16);
        }
    }
    // bias regs for this wave's 64 cols
    const int cb = ch * 128 + cg * 64;
    float bfv[4], biv[4];
#pragma unroll
    for (int nt = 0; nt < 4; ++nt) {
        bfv[nt] = Bf[cb + nt * 16 + r];
        biv[nt] = Bi[cb + nt * 16 + r];
    }
    __syncthreads();                          // the ONLY barrier

    const short* bpf = lw + q * 1024 + (cg * 64 + r) * 8;   // mat f (Wf)
    const short* bpi = bpf + 32768;                          // mat i (Wi)

#pragma unroll
    for (int tt = 0; tt < 5; ++tt) {
        const int row = p0 + tt * 64 + rg * 16 + r;
        const short* x3r = (const short*)X3 + (size_t)row * DIM + q * 8;
        const float* rsr = RES + (size_t)row * DIM + q * 8;

        // burst-issue all A loads for this tile (24 loads), cvt deferred
        bf16x8 a1[8];
        float4 rw[16];
#pragma unroll
        for (int kk = 0; kk < 8; ++kk) {
            rw[2*kk]   = ((const float4*)rsr)[kk * 8];
            rw[2*kk+1] = ((const float4*)rsr)[kk * 8 + 1];
            a1[kk] = *(const bf16x8*)(x3r + kk * 32);
        }

        f32x4 acc1[4], acc2[4];
#pragma unroll
        for (int nt = 0; nt < 4; ++nt) {
            acc1[nt] = (f32x4){0.f,0.f,0.f,0.f};
            acc2[nt] = (f32x4){0.f,0.f,0.f,0.f};
        }
#pragma unroll
        for (int kk = 0; kk < 8; ++kk) {
            bf16x8 a2;
            {
                const float4 lo = rw[2*kk], hi = rw[2*kk+1];
                a2[0]=f2bs(lo.x); a2[1]=f2bs(lo.y); a2[2]=f2bs(lo.z); a2[3]=f2bs(lo.w);
                a2[4]=f2bs(hi.x); a2[5]=f2bs(hi.y); a2[6]=f2bs(hi.z); a2[7]=f2bs(hi.w);
            }
#pragma unroll
            for (int nt = 0; nt < 4; ++nt) {
                bf16x8 b1 = *(const bf16x8*)(bpf + kk * 4096 + nt * 128);
                bf16x8 b2 = *(const bf16x8*)(bpi + kk * 4096 + nt * 128);
                acc1[nt] = __builtin_amdgcn_mfma_f32_16x16x32_bf16(a1[kk], b1, acc1[nt], 0, 0, 0);
                acc2[nt] = __builtin_amdgcn_mfma_f32_16x16x32_bf16(a2,    b2, acc2[nt], 0, 0, 0);
            }
        }
        // epilogue: 16 rows x 64 cols per wave
#pragma unroll
        for (int nt = 0; nt < 4; ++nt) {
            const int col = cb + nt * 16 + r;
#pragma unroll
            for (int i = 0; i < 4; ++i) {
                float v = lrelu(acc1[nt][i] + bfv[nt]) + lrelu(acc2[nt][i] + biv[nt]);
                OUT[(size_t)(p0 + tt * 64 + rg * 16 + q * 4 + i) * DIM + col] = v;
            }
        }
    }
}

// ---------------------------------------------------------------------------
extern "C" void kernel_launch(void* const* d_in, const int* in_sizes, int n_in,
                              void* d_out, int out_size, void* d_ws, size_t ws_size,
                              hipStream_t stream)
{
    const float* input  = (const float*)d_in[0];   // [2,20000,256]
    const float* geom   = (const float*)d_in[1];   // [2,20000,16,4]
    const int*   idxw   = (const int*)d_in[2];     // int32/int64 (detected)
    const float* W_init = (const float*)d_in[3];   // [64,256]
    const float* b_init = (const float*)d_in[4];
    const float* W_l1   = (const float*)d_in[5];   // [64,4]
    const float* b_l1   = (const float*)d_in[6];
    const float* W_l2   = (const float*)d_in[7];   // [128,4]
    const float* b_l2   = (const float*)d_in[8];
    const float* W_fin  = (const float*)d_in[9];   // [256,256]
    const float* b_fin  = (const float*)d_in[10];
    const float* W_id   = (const float*)d_in[11];  // [256,256]
    const float* b_id   = (const float*)d_in[12];
    float* out = (float*)d_out;                    // [2,20000,256] fp32

    // ws layout (<= 35.84 MB, proven safe R4-R10):
    //   flag @0 (16B)
    //   Wt  tiled bf16 256KB @16 ; Wnt tiled bf16 32KB @16+262144
    //   x2  [BN,128] bf16 @16+5.12e6
    //   x3  [BN,256] bf16 @16+15.36e6
    // x1 [BN,64] bf16 lives in d_out scratch; consumed by gather1, then
    // final_mfma overwrites all of d_out.
    char* ws = (char*)d_ws;
    int* flag = (int*)ws;
    short* Wt  = (short*)(ws + 16);
    short* Wnt = (short*)(ws + 16 + 262144);
    __hip_bfloat16* x2 = (__hip_bfloat16*)(ws + 16 + 5120000);
    __hip_bfloat16* x3 = (__hip_bfloat16*)(ws + 16 + 15360000);
    __hip_bfloat16* x1 = (__hip_bfloat16*)d_out;   // scratch, dead after gather1

    prep_kernel<<<145, 256, 0, stream>>>(idxw, flag, W_fin, W_id, W_init,
                                         Wt, Wnt);
    stage2_kernel<<<1250, 256, 0, stream>>>(geom, W_l1, b_l1, W_l2, b_l2,
                                            input, Wnt, b_init, x2, x3, x1);
    gather1_kernel<<<1250, 256, 0, stream>>>(idxw, flag, x1, x2);
    gather2_kernel<<<2500, 256, 0, stream>>>(idxw, flag, x2, x3);
    final_mfma<<<250, 512, 0, stream>>>(x3, input, Wt, b_fin, b_id, out);
}